// Round 8
// baseline (221.155 us; speedup 1.0000x reference)
//
#include <hip/hip_runtime.h>

#define HW (1024 * 1024)
#define PLANE 8388608   // C * WS * WS = 512 * 16384

typedef _Float16 half4 __attribute__((ext_vector_type(4)));
typedef _Float16 half8 __attribute__((ext_vector_type(8)));
typedef float floatx4 __attribute__((ext_vector_type(4)));

// d_ws layout: int counts[8] @0; int lists[8][4096] @16 ints; X16 @256 KB.
// X16: (1024*1024, 8) fp16 px-major = {x0..x5, sigma, 0} -> 16 B/px, 16 MB.

// K0: bucket the 4096 (window, 16-row-group) pairs by image band (128 rows).
__global__ __launch_bounds__(512) void build_worklist(
    const int* __restrict__ cent, int* __restrict__ ws)
{
    __shared__ int cnt[8];
    if (threadIdx.x < 8) cnt[threadIdx.x] = 0;
    __syncthreads();
    for (int t = threadIdx.x; t < 4096; t += 512) {
        const int w = t >> 3, g = t & 7;
        const int cy0 = min(max(cent[2 * w], 64), 960) - 64;
        const int mid = cy0 + 16 * g + 8;        // group midpoint row
        const int d = mid >> 7;                  // band 0..7
        const int slot = atomicAdd(&cnt[d], 1);
        ws[16 + d * 4096 + slot] = t;
    }
    __syncthreads();
    if (threadIdx.x < 8) ws[threadIdx.x] = cnt[threadIdx.x];
}

// K1: pack xs -> fp16 px-major, band-pinned (blockIdx.x = band -> XCD linear%8).
__global__ __launch_bounds__(256) void prep(
    const float* __restrict__ x,      // (6, 1024, 1024)
    const float* __restrict__ sigma,  // (1, 1024, 1024)
    _Float16* __restrict__ X16)       // (1024*1024, 8)
{
    const int px = blockIdx.x * 131072 + blockIdx.y * 256 + threadIdx.x;
    half8 v;
#pragma unroll
    for (int e = 0; e < 6; ++e) v[e] = (_Float16)x[e * HW + px];
    v[6] = (_Float16)sigma[px];
    v[7] = (_Float16)0.0f;
    *(half8*)(X16 + (size_t)px * 8) = v;
}

// K2: grid (8, 128+1024). blockIdx.x = band d (-> XCD d).
//   by <  128 : iidd role — nontemporal writes of the 3 index planes.
//   by >= 128 : MLP role — worklist entries of band d, strided by 1024.
//   Per 16-px chain: B1 = X16 tile (quads 2,3 zero) -> C1 = W1^T B1 (MFMA)
//   -> h1 = relu(C1 + qf) -> MFMA2 with W2^T -> W3 dot + sigmoid.
__global__ __launch_bounds__(256) void mlp(
    const _Float16* __restrict__ X16,
    const int* __restrict__ ws,       // counts + lists
    const float* __restrict__ c,      // (512, 6)
    const float* __restrict__ W1,     // (7, 16)
    const float* __restrict__ b1,     // (16)
    const float* __restrict__ W2,     // (16, 16)
    const float* __restrict__ b2,     // (16)
    const float* __restrict__ W3,     // (16, 1)
    const float* __restrict__ b3,     // (1)
    const int*   __restrict__ cent,   // (512, 2)
    float* __restrict__ out)
{
    const int d = blockIdx.x;

    if (blockIdx.y < 128) {
        // ---- iidd role: 1024 blocks, each writes half a window's 3 planes
        const int j    = d * 128 + blockIdx.y;
        const int w    = j >> 1;
        const int half = j & 1;
        const int cy0 = min(max(cent[2 * w], 64), 960) - 64;
        const int cx0 = min(max(cent[2 * w + 1], 64), 960) - 64;
        const float iw = (float)w;
#pragma unroll
        for (int pass = 0; pass < 8; ++pass) {
            const int p = half * 8192 + pass * 1024 + threadIdx.x * 4;
            const int n = w * 16384 + p;
            const float row = (float)(cy0 + (p >> 7));
            const float c0  = (float)(cx0 + (p & 127));
            floatx4 iv = {iw, iw, iw, iw};
            floatx4 rv = {row, row, row, row};
            floatx4 cv = {c0, c0 + 1.0f, c0 + 2.0f, c0 + 3.0f};
            __builtin_nontemporal_store(iv, (floatx4*)(out + PLANE + n));
            __builtin_nontemporal_store(rv, (floatx4*)(out + 2 * PLANE + n));
            __builtin_nontemporal_store(cv, (floatx4*)(out + 3 * PLANE + n));
        }
        return;
    }

    const int lane = threadIdx.x & 63;
    const int wave = threadIdx.x >> 6;
    const int quad = lane >> 4;
    const int sub  = lane & 15;
    const bool hiq = quad >= 2;       // quads 2,3 carry k=8..15 (all zero)

    // A1[m=sub][k=4q+i] = W1[k][sub] (k<7);  A2[m=sub][k=4q+i] = W2[k][m]
    half4 a1, a2;
    float w3f[4], bb2[4];
#pragma unroll
    for (int ii = 0; ii < 4; ++ii) {
        const int k = 4 * quad + ii;
        a1[ii]  = (_Float16)((k < 7) ? W1[k * 16 + sub] : 0.0f);
        a2[ii]  = (_Float16)W2[k * 16 + sub];
        w3f[ii] = W3[k];
        bb2[ii] = b2[k];
    }
    const float b3v = b3[0];
    const floatx4 zero = {0.0f, 0.0f, 0.0f, 0.0f};

    const int count = ws[d];
    for (int i = blockIdx.y - 128; i < count; i += 1024) {
        const int t = ws[16 + d * 4096 + i];
        const int w = t >> 3, g = t & 7;

        const int cy0 = min(max(cent[2 * w], 64), 960) - 64;
        const int cx0 = min(max(cent[2 * w + 1], 64), 960) - 64;

        // qf[j] = b1[j] - sum_e W1[e][j]*c[w][e], j = 4*quad+ii
        float qf[4];
#pragma unroll
        for (int ii = 0; ii < 4; ++ii) {
            const int k = 4 * quad + ii;
            float qv = b1[k];
#pragma unroll
            for (int e = 0; e < 6; ++e)
                qv = fmaf(-W1[e * 16 + k], c[w * 6 + e], qv);
            qf[ii] = qv;
        }

        // window rows 16g..16g+15 = window-pixels [g*2048, g*2048+2048)
        for (int it = wave; it < 32; it += 4) {
            const int start = g * 2048 + it * 64;     // one window row, 64 px
            const int srcbase = (cy0 + (start >> 7)) * 1024 + cx0 + (start & 127);
            const _Float16* xb = X16 + (size_t)(srcbase + sub) * 8 + (quad & 1) * 4;

            float logit[4];
#pragma unroll
            for (int ch = 0; ch < 4; ++ch) {
                // B1: channels 4q..4q+3 of pixel (sub + 16*ch); 16 px = 128B imm
                half4 bx = *(const half4*)(xb + ch * 128);
                if (hiq) bx = half4{0, 0, 0, 0};

                floatx4 c1 = __builtin_amdgcn_mfma_f32_16x16x16f16(a1, bx, zero, 0, 0, 0);

                half4 h;
#pragma unroll
                for (int ii = 0; ii < 4; ++ii)
                    h[ii] = (_Float16)fmaxf(c1[ii] + qf[ii], 0.0f);

                floatx4 c2 = __builtin_amdgcn_mfma_f32_16x16x16f16(a2, h, zero, 0, 0, 0);

                float part = 0.0f;
#pragma unroll
                for (int ii = 0; ii < 4; ++ii)
                    part = fmaf(w3f[ii], fmaxf(c2[ii] + bb2[ii], 0.0f), part);
                part += __shfl_xor(part, 16, 64);
                part += __shfl_xor(part, 32, 64);
                logit[ch] = part;
            }

            const float l01 = (quad & 1) ? logit[1] : logit[0];
            const float l23 = (quad & 1) ? logit[3] : logit[2];
            const float lg  = (quad & 2) ? l23 : l01;
            const float prob = __builtin_amdgcn_rcpf(1.0f + __expf(-(lg + b3v)));

            __builtin_nontemporal_store(prob, out + w * 16384 + start + lane);
        }
    }
}

extern "C" void kernel_launch(void* const* d_in, const int* in_sizes, int n_in,
                              void* d_out, int out_size, void* d_ws, size_t ws_size,
                              hipStream_t stream) {
    const float* x     = (const float*)d_in[0];
    const float* sigma = (const float*)d_in[1];
    const float* c     = (const float*)d_in[2];
    const float* W1    = (const float*)d_in[3];
    const float* b1    = (const float*)d_in[4];
    const float* W2    = (const float*)d_in[5];
    const float* b2    = (const float*)d_in[6];
    const float* W3    = (const float*)d_in[7];
    const float* b3    = (const float*)d_in[8];
    const int*   cent  = (const int*)d_in[9];
    float* out = (float*)d_out;

    int* wsl       = (int*)d_ws;                        // counts + worklists
    _Float16* X16  = (_Float16*)((char*)d_ws + 262144); // 16 MB fp16 packed

    build_worklist<<<dim3(1), dim3(512), 0, stream>>>(cent, wsl);
    prep<<<dim3(8, 512), dim3(256), 0, stream>>>(x, sigma, X16);
    mlp<<<dim3(8, 1152), dim3(256), 0, stream>>>(
        X16, wsl, c, W1, b1, W2, b2, W3, b3, cent, out);
}